// Round 14
// baseline (4078.902 us; speedup 1.0000x reference)
//
#include <hip/hip_runtime.h>
#include <hip/hip_bf16.h>
#include <stdint.h>

// Problem constants
#define NB 64      // batch
#define NT 128     // seq len
#define NE 512     // embed
#define NH 1024    // hidden
#define NV 32000   // vocab
#define NM (NB*NT) // 8192 flattened (t-major: m = t*64 + b)

// Config: 256 wgs (1/CU), 512 threads. Waves 0-3 = half 0 (group 0, batches
// 0-31), waves 4-7 = half 1 (group 1, batches 32-63). Each wg owns units
// wg*4..wg*4+4 per layer (16 gate-rows = one 16-col MFMA B-tile), with each
// role wave's full B-slice in 128 breg registers -> no weight LDS.
// Halves are fully decoupled: no __syncthreads in the scan; per-half LDS
// cumulative-counter barriers + per-half grid flags. While one half waits on
// its grid flags, the other half's waves keep the SIMDs busy.
#define NWG 256
#define NTH 512
#define FLAG_STRIDE 32u    // one flag per 128-B LLC line

// History slots per group, write-once, FRAGMENT-MAJOR (shorts):
// offset (rb,kk,lane,j) = ((rb*32+kk)*64+lane)*8+j holds
// h[g*32 + rb*16 + (lane&15)][kk*32 + (lane>>4)*8 + j].
#define HS_SHORTS 32768u                        // 64 KB slot (32 batches x 1024 u)
#define GSTRIDE_SH (129u*HS_SHORTS)             // shorts per group history
#define WS_FLAGS_S 0u                           // 32 KB startup flags
#define WS_FLAGS_G 32768u                       // 2 groups x 256 flags x 128 B = 64 KB
#define WS_H0      131072u
#define WS_H1      (WS_H0 + 2u*129u*65536u)
#define WS_CNT     (WS_H1 + 2u*129u*65536u)
#define WS_XS0     (WS_CNT + 4u*NB*NV)
#define WS_NEEDED  (WS_XS0 + 2u*NM*NE)

typedef __attribute__((ext_vector_type(8))) short bf16x8;
typedef __attribute__((ext_vector_type(4))) float f32x4;

#define SCOPE_AG  __HIP_MEMORY_SCOPE_AGENT
#define SCOPE_WG  __HIP_MEMORY_SCOPE_WORKGROUP

__device__ __forceinline__ unsigned short f2bf(float f) {
  unsigned u = __float_as_uint(f);
  u += 0x7FFFu + ((u >> 16) & 1u);   // round-nearest-even
  return (unsigned short)(u >> 16);
}
__device__ __forceinline__ float sigmoidf_(float x) {
  return 1.0f / (1.0f + expf(-x));
}
__device__ __forceinline__ bf16x8 pack8(float4 a, float4 b) {
  bf16x8 v;
  v[0]=(short)f2bf(a.x); v[1]=(short)f2bf(a.y); v[2]=(short)f2bf(a.z); v[3]=(short)f2bf(a.w);
  v[4]=(short)f2bf(b.x); v[5]=(short)f2bf(b.y); v[6]=(short)f2bf(b.z); v[7]=(short)f2bf(b.w);
  return v;
}

#define MFMA(a,b,c) __builtin_amdgcn_mfma_f32_16x16x32_bf16((a),(b),(c),0,0,0)
#define VM0()  do { asm volatile("s_waitcnt vmcnt(0)" ::: "memory"); } while (0)
#define SCHED() __builtin_amdgcn_sched_barrier(0)

__global__ void __launch_bounds__(NTH, 2)
lstm_all(const int* __restrict__ x, const float* __restrict__ emb,
         const float* __restrict__ w_ih0, const float* __restrict__ w_hh0,
         const float* __restrict__ b_ih0, const float* __restrict__ b_hh0,
         const float* __restrict__ w_ih1, const float* __restrict__ w_hh1,
         const float* __restrict__ b_ih1, const float* __restrict__ b_hh1,
         const float* __restrict__ fc_w, const float* __restrict__ fc_b,
         float* __restrict__ out, unsigned char* __restrict__ wsb)
{
  // LDS ~17 KB total
  __shared__ float sG0[2][32][16], sGih[2][32][16], sG1a[2][32][16], sG1b[2][32][16];
  __shared__ float sB0[16], sB1[16];
  __shared__ unsigned sCnt[4];   // [h]=MFMA arrivals, [2+h]=publish arrivals (cumulative)

  const int wg  = blockIdx.x;
  const int tid = threadIdx.x;
  const int wave = tid >> 6, lane = tid & 63;
  const int lr = lane & 15, lq = lane >> 4;
  const int h    = wave >> 2;     // half = group
  const int role = wave & 3;      // 0:hh1  1:hh0  2:ih1  3:ih0

  unsigned* flagsS = (unsigned*)(wsb + WS_FLAGS_S);
  unsigned* gfg    = (unsigned*)(wsb + WS_FLAGS_G) + (unsigned)h*NWG*FLAG_STRIDE;
  unsigned short* h0g = (unsigned short*)(wsb + WS_H0) + (size_t)h*GSTRIDE_SH;
  unsigned short* h1g = (unsigned short*)(wsb + WS_H1) + (size_t)h*GSTRIDE_SH;
  unsigned* counts = (unsigned*)(wsb + WS_CNT);
  unsigned short* xs0 = (unsigned short*)(wsb + WS_XS0);

  if (tid < 4) sCnt[tid] = 0;

  // ---- breg: full B-slice (16 gate-rows = 4 units x 4 gates) per role wave.
  // col c = lane&15: source row = (c>>2)*NH + wg*4 + (c&3).
  bf16x8 breg[32];
  {
    const int rowW = (lr >> 2)*NH + wg*4 + (lr & 3);
    const float* src;
    int nkk;
    if      (role == 0) { src = w_hh1 + (size_t)rowW*NH; nkk = 32; }
    else if (role == 1) { src = w_hh0 + (size_t)rowW*NH; nkk = 32; }
    else if (role == 2) { src = w_ih1 + (size_t)rowW*NH; nkk = 32; }
    else                { src = w_ih0 + (size_t)rowW*NE; nkk = 16; }
    src += lq*8;
    for (int kk = 0; kk < nkk; ++kk)
      breg[kk] = pack8(*(const float4*)(src + kk*32), *(const float4*)(src + kk*32 + 4));
  }

  // ---- gather embeddings -> xs0 (bf16, per-group fragment-major), sc1 ----
  for (int i = wg*NTH + tid; i < NM*(NE/8); i += NWG*NTH) {
    int m = i >> 6;
    int e8 = (i & 63) << 3;
    int t = m >> 6, b = m & 63;
    int tok = x[b*NT + t];
    const float* s = emb + (size_t)tok*NE + e8;
    union { bf16x8 v8; unsigned long long u[2]; } u;
    u.v8 = pack8(*(const float4*)s, *(const float4*)(s + 4));
    int gg = b >> 5, bb = b & 31;
    size_t off = ((size_t)((gg*NT + t)*2 + (bb >> 4)))*8192
               + ((size_t)((e8 >> 5)*64 + ((e8 >> 3) & 3)*16 + (bb & 15)))*8;
    unsigned long long* dst = (unsigned long long*)(xs0 + off);
    __hip_atomic_store(dst,   u.u[0], __ATOMIC_RELAXED, SCOPE_AG);
    __hip_atomic_store(dst+1, u.u[1], __ATOMIC_RELAXED, SCOPE_AG);
  }

  // ---- biases ----
  if (tid < 16) {
    int rowW = (tid >> 2)*NH + wg*4 + (tid & 3);
    sB0[tid] = b_ih0[rowW] + b_hh0[rowW];
    sB1[tid] = b_ih1[rowW] + b_hh1[rowW];
  }
  // ---- token histogram ----
  {
    int i = wg*NTH + tid;
    if (i < NB*NT) {
      int b = i >> 7;
      atomicAdd(&counts[(size_t)b*NV + x[i]], 1u);
    }
  }
  // ---- startup: GLOBAL barrier (gather written by all wgs) ----
  __syncthreads();
  if (tid == 0)
    __hip_atomic_store(&flagsS[(unsigned)wg * FLAG_STRIDE], 1u, __ATOMIC_RELAXED, SCOPE_AG);
  if (tid < NWG) {
    while (__hip_atomic_load(&flagsS[(unsigned)tid * FLAG_STRIDE], __ATOMIC_RELAXED, SCOPE_AG) < 1u)
      __builtin_amdgcn_s_sleep(8);
  }
  __syncthreads();

  // cell identity: within half, threads 0-127 = layer0, 128-255 = layer1;
  // ci = 4*batch + unit (4 consecutive lanes per batch row).
  const int tid256 = tid & 255;
  const int layer = tid256 >> 7;
  const int ci = tid256 & 127;
  const int cb = ci >> 2, cu = ci & 3;
  const size_t pub16 = ((size_t)((cb >> 4)*32 + (wg >> 3))*64 + ((wg >> 1) & 3)*16 + (cb & 15))*8
                     + (wg & 1)*4;
  float c_reg = 0.f;

  // ================= scan: 129 steps, NO __syncthreads =================
  for (int t = 0; t <= NT; ++t) {
    // ---- MFMA phase (role wave, both rb) ----
    if (role == 1) {            // a0 = hist0[t] @ w_hh0 (layer0 time t)
      if (t < NT) {
        #pragma unroll
        for (int rb = 0; rb < 2; ++rb) {
          const unsigned short* A = h0g + (size_t)t*HS_SHORTS + rb*16384 + lane*8;
          f32x4 a = {0.f,0.f,0.f,0.f};
          #pragma unroll
          for (int kk = 0; kk < 32; ++kk)
            a = MFMA(*(const bf16x8*)(A + kk*512), breg[kk], a);
          #pragma unroll
          for (int r = 0; r < 4; ++r) sG0[h][rb*16 + lq*4 + r][lr] = a[r];
        }
      }
    } else if (role == 2) {     // a1 = hist0[t] @ w_ih1 (layer1 time t-1)
      if (t >= 1) {
        #pragma unroll
        for (int rb = 0; rb < 2; ++rb) {
          const unsigned short* A = h0g + (size_t)t*HS_SHORTS + rb*16384 + lane*8;
          f32x4 a = {0.f,0.f,0.f,0.f};
          #pragma unroll
          for (int kk = 0; kk < 32; ++kk)
            a = MFMA(*(const bf16x8*)(A + kk*512), breg[kk], a);
          #pragma unroll
          for (int r = 0; r < 4; ++r) sG1a[h][rb*16 + lq*4 + r][lr] = a[r];
        }
      }
    } else if (role == 0) {     // a2 = hist1[t-1] @ w_hh1 (layer1 time t-1)
      if (t >= 1) {
        #pragma unroll
        for (int rb = 0; rb < 2; ++rb) {
          const unsigned short* A = h1g + (size_t)(t-1)*HS_SHORTS + rb*16384 + lane*8;
          f32x4 a = {0.f,0.f,0.f,0.f};
          #pragma unroll
          for (int kk = 0; kk < 32; ++kk)
            a = MFMA(*(const bf16x8*)(A + kk*512), breg[kk], a);
          #pragma unroll
          for (int r = 0; r < 4; ++r) sG1b[h][rb*16 + lq*4 + r][lr] = a[r];
        }
      }
    } else {                    // ai = xs[t] @ w_ih0 (layer0 time t)
      if (t < NT) {
        #pragma unroll
        for (int rb = 0; rb < 2; ++rb) {
          const unsigned short* A = xs0 + ((size_t)((h*NT + t)*2 + rb))*8192 + lane*8;
          f32x4 a = {0.f,0.f,0.f,0.f};
          #pragma unroll
          for (int kk = 0; kk < 16; ++kk)
            a = MFMA(*(const bf16x8*)(A + kk*512), breg[kk], a);
          #pragma unroll
          for (int r = 0; r < 4; ++r) sGih[h][rb*16 + lq*4 + r][lr] = a[r];
        }
      }
    }
    // ---- barM: sG complete within half (release add / acquire spin) ----
    if (lane == 0)
      __hip_atomic_fetch_add(&sCnt[h], 1u, __ATOMIC_RELEASE, SCOPE_WG);
    while (__hip_atomic_load(&sCnt[h], __ATOMIC_ACQUIRE, SCOPE_WG) < 4u*(unsigned)(t+1)) {}
    SCHED();
    // ---- cells + fused publish ----
    if (layer == 0) {
      if (t < NT) {
        float gi = sG0[h][cb][cu]    + sGih[h][cb][cu]    + sB0[cu];
        float gf = sG0[h][cb][4+cu]  + sGih[h][cb][4+cu]  + sB0[4+cu];
        float gg = sG0[h][cb][8+cu]  + sGih[h][cb][8+cu]  + sB0[8+cu];
        float go = sG0[h][cb][12+cu] + sGih[h][cb][12+cu] + sB0[12+cu];
        float ii = sigmoidf_(gi), ff = sigmoidf_(gf), gv = tanhf(gg), oo = sigmoidf_(go);
        c_reg = ff*c_reg + ii*gv;
        unsigned hb = f2bf(oo * tanhf(c_reg));
        unsigned o1 = (unsigned)__shfl_down((int)hb, 1);
        unsigned o2 = (unsigned)__shfl_down((int)hb, 2);
        unsigned o3 = (unsigned)__shfl_down((int)hb, 3);
        if (cu == 0) {
          unsigned long long v = (unsigned long long)(hb | (o1 << 16))
                               | ((unsigned long long)(o2 | (o3 << 16)) << 32);
          __hip_atomic_store((unsigned long long*)(h0g + (size_t)(t+1)*HS_SHORTS + pub16),
                             v, __ATOMIC_RELAXED, SCOPE_AG);
        }
      }
    } else {
      if (t >= 1) {
        float gi = sG1a[h][cb][cu]    + sG1b[h][cb][cu]    + sB1[cu];
        float gf = sG1a[h][cb][4+cu]  + sG1b[h][cb][4+cu]  + sB1[4+cu];
        float gg = sG1a[h][cb][8+cu]  + sG1b[h][cb][8+cu]  + sB1[8+cu];
        float go = sG1a[h][cb][12+cu] + sG1b[h][cb][12+cu] + sB1[12+cu];
        float ii = sigmoidf_(gi), ff = sigmoidf_(gf), gv = tanhf(gg), oo = sigmoidf_(go);
        c_reg = ff*c_reg + ii*gv;
        unsigned hb = f2bf(oo * tanhf(c_reg));
        unsigned o1 = (unsigned)__shfl_down((int)hb, 1);
        unsigned o2 = (unsigned)__shfl_down((int)hb, 2);
        unsigned o3 = (unsigned)__shfl_down((int)hb, 3);
        if (cu == 0) {
          unsigned long long v = (unsigned long long)(hb | (o1 << 16))
                               | ((unsigned long long)(o2 | (o3 << 16)) << 32);
          __hip_atomic_store((unsigned long long*)(h1g + (size_t)t*HS_SHORTS + pub16),
                             v, __ATOMIC_RELAXED, SCOPE_AG);
        }
      }
    }
    // ---- barP: publishes at LLC before flag (manual vmcnt drain) ----
    VM0();
    if (lane == 0)
      __hip_atomic_fetch_add(&sCnt[2+h], 1u, __ATOMIC_RELEASE, SCOPE_WG);
    if (role == 0) {   // wave h*4: waits for all 4 arrivals, then flags
      while (__hip_atomic_load(&sCnt[2+h], __ATOMIC_ACQUIRE, SCOPE_WG) < 4u*(unsigned)(t+1)) {}
      SCHED();
      if (lane == 0)
        __hip_atomic_store(&gfg[(unsigned)wg * FLAG_STRIDE], (unsigned)(t+1),
                           __ATOMIC_RELAXED, SCOPE_AG);
    }
    // ---- grid poll: every wave, 4 flags/lane (256 wgs), batched loads ----
    {
      const unsigned need = (unsigned)(t+1);
      for (;;) {
        unsigned f0 = __hip_atomic_load(&gfg[(unsigned)lane*FLAG_STRIDE],        __ATOMIC_RELAXED, SCOPE_AG);
        unsigned f1 = __hip_atomic_load(&gfg[(unsigned)(lane+64)*FLAG_STRIDE],   __ATOMIC_RELAXED, SCOPE_AG);
        unsigned f2 = __hip_atomic_load(&gfg[(unsigned)(lane+128)*FLAG_STRIDE],  __ATOMIC_RELAXED, SCOPE_AG);
        unsigned f3 = __hip_atomic_load(&gfg[(unsigned)(lane+192)*FLAG_STRIDE],  __ATOMIC_RELAXED, SCOPE_AG);
        if (__all(f0 >= need && f1 >= need && f2 >= need && f3 >= need)) break;
        __builtin_amdgcn_s_sleep(1);
      }
      SCHED();
    }
  }

  // ---- FC + repetition penalty (own group's h1[127] = slot 128) ----
  {
    const unsigned short* ab = h1g + (size_t)128*HS_SHORTS + lane*8;
    for (int tile = wg*4 + role; tile < NV/16; tile += 1024) {
      int c0 = tile*16;
      const float* wb = fc_w + (size_t)(c0 + lr)*NH + lq*8;
      f32x4 acc0 = {0.f,0.f,0.f,0.f}, acc1 = {0.f,0.f,0.f,0.f};
      #pragma unroll 4
      for (int kk = 0; kk < 32; ++kk) {
        bf16x8 bfv = pack8(*(const float4*)(wb + kk*32), *(const float4*)(wb + kk*32 + 4));
        acc0 = MFMA(*(const bf16x8*)(ab + kk*512),         bfv, acc0);
        acc1 = MFMA(*(const bf16x8*)(ab + 16384 + kk*512), bfv, acc1);
      }
      int c = c0 + lr;
      float fb = fc_b[c];
      #pragma unroll
      for (int r = 0; r < 4; ++r) {
        int b0 = h*32 + lq*4 + r;          // rb = 0
        int b1 = b0 + 16;                  // rb = 1
        unsigned cnt0 = counts[(size_t)b0*NV + c];
        unsigned cnt1 = counts[(size_t)b1*NV + c];
        out[(size_t)b0*NV + c] = (acc0[r] + fb) * exp2f(-0.26303440583379378f * (float)cnt0);
        out[(size_t)b1*NV + c] = (acc1[r] + fb) * exp2f(-0.26303440583379378f * (float)cnt1);
      }
    }
  }
}

extern "C" void kernel_launch(void* const* d_in, const int* in_sizes, int n_in,
                              void* d_out, int out_size, void* d_ws, size_t ws_size,
                              hipStream_t stream) {
  const int*   x     = (const int*)  d_in[0];
  const float* emb   = (const float*)d_in[1];
  const float* w_ih0 = (const float*)d_in[2];
  const float* w_hh0 = (const float*)d_in[3];
  const float* b_ih0 = (const float*)d_in[4];
  const float* b_hh0 = (const float*)d_in[5];
  const float* w_ih1 = (const float*)d_in[6];
  const float* w_hh1 = (const float*)d_in[7];
  const float* b_ih1 = (const float*)d_in[8];
  const float* b_hh1 = (const float*)d_in[9];
  const float* fc_w  = (const float*)d_in[10];
  const float* fc_b  = (const float*)d_in[11];
  if (ws_size < WS_NEEDED) return;
  unsigned char* ws = (unsigned char*)d_ws;
  (void)hipMemsetAsync(ws, 0, WS_H0, stream);                          // all flag arrays
  (void)hipMemsetAsync(ws + WS_H0, 0, 65536, stream);                  // hist0 g0 slot 0
  (void)hipMemsetAsync(ws + WS_H0 + 129u*65536u, 0, 65536, stream);    // hist0 g1 slot 0
  (void)hipMemsetAsync(ws + WS_H1, 0, 65536, stream);                  // hist1 g0 slot 0
  (void)hipMemsetAsync(ws + WS_H1 + 129u*65536u, 0, 65536, stream);    // hist1 g1 slot 0
  (void)hipMemsetAsync(ws + WS_CNT, 0, 4u*NB*NV, stream);              // token histogram
  hipLaunchKernelGGL(lstm_all, dim3(NWG), dim3(NTH), 0, stream,
                     x, emb, w_ih0, w_hh0, b_ih0, b_hh0,
                     w_ih1, w_hh1, b_ih1, b_hh1, fc_w, fc_b,
                     (float*)d_out, (unsigned char*)d_ws);
}

// Round 15
// 2077.345 us; speedup vs baseline: 1.9635x; 1.9635x over previous
//
#include <hip/hip_runtime.h>
#include <hip/hip_bf16.h>
#include <stdint.h>

// Problem constants
#define NB 64      // batch
#define NT 128     // seq len
#define NE 512     // embed
#define NH 1024    // hidden
#define NV 32000   // vocab
#define NM (NB*NT) // 8192 flattened (t-major: m = t*64 + b)

// Config: 256 wgs (1/CU), 512 threads. Waves 0-3 = half 0 (group 0, batches
// 0-31), waves 4-7 = half 1 (group 1, batches 32-63). Each wg owns units
// wg*4..wg*4+4 per layer; each role wave's full B-slice lives in 128 breg
// VGPRs (fill loops MUST be constant-bound + unrolled — r14's runtime-bound
// fill demoted breg to re-materialized global loads: VGPR 52, FETCH 7 GB).
// Halves are fully decoupled: no __syncthreads in the scan; per-half LDS
// cumulative-counter barriers + per-half grid flags. While one half waits on
// its grid flags, the other half's waves keep the SIMDs busy.
#define NWG 256
#define NTH 512
#define FLAG_STRIDE 32u    // one flag per 128-B LLC line

// History slots per group, write-once, FRAGMENT-MAJOR (shorts):
// offset (rb,kk,lane,j) = ((rb*32+kk)*64+lane)*8+j holds
// h[g*32 + rb*16 + (lane&15)][kk*32 + (lane>>4)*8 + j].
#define HS_SHORTS 32768u                        // 64 KB slot (32 batches x 1024 u)
#define GSTRIDE_SH (129u*HS_SHORTS)             // shorts per group history
#define WS_FLAGS_S 0u                           // 32 KB startup flags
#define WS_FLAGS_G 32768u                       // 2 groups x 256 flags x 128 B = 64 KB
#define WS_H0      131072u
#define WS_H1      (WS_H0 + 2u*129u*65536u)
#define WS_CNT     (WS_H1 + 2u*129u*65536u)
#define WS_XS0     (WS_CNT + 4u*NB*NV)
#define WS_NEEDED  (WS_XS0 + 2u*NM*NE)

typedef __attribute__((ext_vector_type(8))) short bf16x8;
typedef __attribute__((ext_vector_type(4))) float f32x4;

#define SCOPE_AG  __HIP_MEMORY_SCOPE_AGENT
#define SCOPE_WG  __HIP_MEMORY_SCOPE_WORKGROUP

__device__ __forceinline__ unsigned short f2bf(float f) {
  unsigned u = __float_as_uint(f);
  u += 0x7FFFu + ((u >> 16) & 1u);   // round-nearest-even
  return (unsigned short)(u >> 16);
}
__device__ __forceinline__ float sigmoidf_(float x) {
  return 1.0f / (1.0f + expf(-x));
}
__device__ __forceinline__ bf16x8 pack8(float4 a, float4 b) {
  bf16x8 v;
  v[0]=(short)f2bf(a.x); v[1]=(short)f2bf(a.y); v[2]=(short)f2bf(a.z); v[3]=(short)f2bf(a.w);
  v[4]=(short)f2bf(b.x); v[5]=(short)f2bf(b.y); v[6]=(short)f2bf(b.z); v[7]=(short)f2bf(b.w);
  return v;
}

#define MFMA(a,b,c) __builtin_amdgcn_mfma_f32_16x16x32_bf16((a),(b),(c),0,0,0)
#define VM0()  do { asm volatile("s_waitcnt vmcnt(0)" ::: "memory"); } while (0)
#define SCHED() __builtin_amdgcn_sched_barrier(0)

__global__ void __launch_bounds__(NTH, 2)
lstm_all(const int* __restrict__ x, const float* __restrict__ emb,
         const float* __restrict__ w_ih0, const float* __restrict__ w_hh0,
         const float* __restrict__ b_ih0, const float* __restrict__ b_hh0,
         const float* __restrict__ w_ih1, const float* __restrict__ w_hh1,
         const float* __restrict__ b_ih1, const float* __restrict__ b_hh1,
         const float* __restrict__ fc_w, const float* __restrict__ fc_b,
         float* __restrict__ out, unsigned char* __restrict__ wsb)
{
  // LDS ~17 KB total
  __shared__ float sG0[2][32][16], sGih[2][32][16], sG1a[2][32][16], sG1b[2][32][16];
  __shared__ float sB0[16], sB1[16];
  __shared__ unsigned sCnt[4];   // [h]=MFMA arrivals, [2+h]=publish arrivals (cumulative)

  const int wg  = blockIdx.x;
  const int tid = threadIdx.x;
  const int wave = tid >> 6, lane = tid & 63;
  const int lr = lane & 15, lq = lane >> 4;
  const int h    = wave >> 2;     // half = group
  const int role = wave & 3;      // 0:hh1  1:hh0  2:ih1  3:ih0

  unsigned* flagsS = (unsigned*)(wsb + WS_FLAGS_S);
  unsigned* gfg    = (unsigned*)(wsb + WS_FLAGS_G) + (unsigned)h*NWG*FLAG_STRIDE;
  unsigned short* h0g = (unsigned short*)(wsb + WS_H0) + (size_t)h*GSTRIDE_SH;
  unsigned short* h1g = (unsigned short*)(wsb + WS_H1) + (size_t)h*GSTRIDE_SH;
  unsigned* counts = (unsigned*)(wsb + WS_CNT);
  unsigned short* xs0 = (unsigned short*)(wsb + WS_XS0);

  if (tid < 4) sCnt[tid] = 0;

  // ---- breg: full B-slice (16 gate-rows = 4 units x 4 gates) per role wave.
  // col c = lane&15: source row = (c>>2)*NH + wg*4 + (c&3).
  // Each branch: constant trip count + #pragma unroll -> register-resident.
  bf16x8 breg[32];
  {
    const int rowW = (lr >> 2)*NH + wg*4 + (lr & 3);
    if (role == 0) {
      const float* src = w_hh1 + (size_t)rowW*NH + lq*8;
      #pragma unroll
      for (int kk = 0; kk < 32; ++kk)
        breg[kk] = pack8(*(const float4*)(src + kk*32), *(const float4*)(src + kk*32 + 4));
    } else if (role == 1) {
      const float* src = w_hh0 + (size_t)rowW*NH + lq*8;
      #pragma unroll
      for (int kk = 0; kk < 32; ++kk)
        breg[kk] = pack8(*(const float4*)(src + kk*32), *(const float4*)(src + kk*32 + 4));
    } else if (role == 2) {
      const float* src = w_ih1 + (size_t)rowW*NH + lq*8;
      #pragma unroll
      for (int kk = 0; kk < 32; ++kk)
        breg[kk] = pack8(*(const float4*)(src + kk*32), *(const float4*)(src + kk*32 + 4));
    } else {
      const float* src = w_ih0 + (size_t)rowW*NE + lq*8;
      #pragma unroll
      for (int kk = 0; kk < 16; ++kk)
        breg[kk] = pack8(*(const float4*)(src + kk*32), *(const float4*)(src + kk*32 + 4));
      #pragma unroll
      for (int kk = 16; kk < 32; ++kk)
        breg[kk] = breg[0];   // defined values; unused by role 3
    }
  }

  // ---- gather embeddings -> xs0 (bf16, per-group fragment-major), sc1 ----
  for (int i = wg*NTH + tid; i < NM*(NE/8); i += NWG*NTH) {
    int m = i >> 6;
    int e8 = (i & 63) << 3;
    int t = m >> 6, b = m & 63;
    int tok = x[b*NT + t];
    const float* s = emb + (size_t)tok*NE + e8;
    union { bf16x8 v8; unsigned long long u[2]; } u;
    u.v8 = pack8(*(const float4*)s, *(const float4*)(s + 4));
    int gg = b >> 5, bb = b & 31;
    size_t off = ((size_t)((gg*NT + t)*2 + (bb >> 4)))*8192
               + ((size_t)((e8 >> 5)*64 + ((e8 >> 3) & 3)*16 + (bb & 15)))*8;
    unsigned long long* dst = (unsigned long long*)(xs0 + off);
    __hip_atomic_store(dst,   u.u[0], __ATOMIC_RELAXED, SCOPE_AG);
    __hip_atomic_store(dst+1, u.u[1], __ATOMIC_RELAXED, SCOPE_AG);
  }

  // ---- biases ----
  if (tid < 16) {
    int rowW = (tid >> 2)*NH + wg*4 + (tid & 3);
    sB0[tid] = b_ih0[rowW] + b_hh0[rowW];
    sB1[tid] = b_ih1[rowW] + b_hh1[rowW];
  }
  // ---- token histogram ----
  {
    int i = wg*NTH + tid;
    if (i < NB*NT) {
      int b = i >> 7;
      atomicAdd(&counts[(size_t)b*NV + x[i]], 1u);
    }
  }
  // ---- startup: GLOBAL barrier (gather written by all wgs) ----
  __syncthreads();
  if (tid == 0)
    __hip_atomic_store(&flagsS[(unsigned)wg * FLAG_STRIDE], 1u, __ATOMIC_RELAXED, SCOPE_AG);
  if (tid < NWG) {
    while (__hip_atomic_load(&flagsS[(unsigned)tid * FLAG_STRIDE], __ATOMIC_RELAXED, SCOPE_AG) < 1u)
      __builtin_amdgcn_s_sleep(8);
  }
  __syncthreads();

  // cell identity: within half, threads 0-127 = layer0, 128-255 = layer1;
  // ci = 4*batch + unit (4 consecutive lanes per batch row).
  const int tid256 = tid & 255;
  const int layer = tid256 >> 7;
  const int ci = tid256 & 127;
  const int cb = ci >> 2, cu = ci & 3;
  const size_t pub16 = ((size_t)((cb >> 4)*32 + (wg >> 3))*64 + ((wg >> 1) & 3)*16 + (cb & 15))*8
                     + (wg & 1)*4;
  float c_reg = 0.f;

  // ================= scan: 129 steps, NO __syncthreads =================
  for (int t = 0; t <= NT; ++t) {
    // ---- MFMA phase (role wave, both rb) ----
    if (role == 1) {            // a0 = hist0[t] @ w_hh0 (layer0 time t)
      if (t < NT) {
        #pragma unroll
        for (int rb = 0; rb < 2; ++rb) {
          const unsigned short* A = h0g + (size_t)t*HS_SHORTS + rb*16384 + lane*8;
          f32x4 a = {0.f,0.f,0.f,0.f};
          #pragma unroll
          for (int kk = 0; kk < 32; ++kk)
            a = MFMA(*(const bf16x8*)(A + kk*512), breg[kk], a);
          #pragma unroll
          for (int r = 0; r < 4; ++r) sG0[h][rb*16 + lq*4 + r][lr] = a[r];
        }
      }
    } else if (role == 2) {     // a1 = hist0[t] @ w_ih1 (layer1 time t-1)
      if (t >= 1) {
        #pragma unroll
        for (int rb = 0; rb < 2; ++rb) {
          const unsigned short* A = h0g + (size_t)t*HS_SHORTS + rb*16384 + lane*8;
          f32x4 a = {0.f,0.f,0.f,0.f};
          #pragma unroll
          for (int kk = 0; kk < 32; ++kk)
            a = MFMA(*(const bf16x8*)(A + kk*512), breg[kk], a);
          #pragma unroll
          for (int r = 0; r < 4; ++r) sG1a[h][rb*16 + lq*4 + r][lr] = a[r];
        }
      }
    } else if (role == 0) {     // a2 = hist1[t-1] @ w_hh1 (layer1 time t-1)
      if (t >= 1) {
        #pragma unroll
        for (int rb = 0; rb < 2; ++rb) {
          const unsigned short* A = h1g + (size_t)(t-1)*HS_SHORTS + rb*16384 + lane*8;
          f32x4 a = {0.f,0.f,0.f,0.f};
          #pragma unroll
          for (int kk = 0; kk < 32; ++kk)
            a = MFMA(*(const bf16x8*)(A + kk*512), breg[kk], a);
          #pragma unroll
          for (int r = 0; r < 4; ++r) sG1b[h][rb*16 + lq*4 + r][lr] = a[r];
        }
      }
    } else {                    // ai = xs[t] @ w_ih0 (layer0 time t)
      if (t < NT) {
        #pragma unroll
        for (int rb = 0; rb < 2; ++rb) {
          const unsigned short* A = xs0 + ((size_t)((h*NT + t)*2 + rb))*8192 + lane*8;
          f32x4 a = {0.f,0.f,0.f,0.f};
          #pragma unroll
          for (int kk = 0; kk < 16; ++kk)
            a = MFMA(*(const bf16x8*)(A + kk*512), breg[kk], a);
          #pragma unroll
          for (int r = 0; r < 4; ++r) sGih[h][rb*16 + lq*4 + r][lr] = a[r];
        }
      }
    }
    // ---- barM: sG complete within half (release add / acquire spin) ----
    if (lane == 0)
      __hip_atomic_fetch_add(&sCnt[h], 1u, __ATOMIC_RELEASE, SCOPE_WG);
    while (__hip_atomic_load(&sCnt[h], __ATOMIC_ACQUIRE, SCOPE_WG) < 4u*(unsigned)(t+1)) {}
    SCHED();
    // ---- cells + fused publish ----
    if (layer == 0) {
      if (t < NT) {
        float gi = sG0[h][cb][cu]    + sGih[h][cb][cu]    + sB0[cu];
        float gf = sG0[h][cb][4+cu]  + sGih[h][cb][4+cu]  + sB0[4+cu];
        float gg = sG0[h][cb][8+cu]  + sGih[h][cb][8+cu]  + sB0[8+cu];
        float go = sG0[h][cb][12+cu] + sGih[h][cb][12+cu] + sB0[12+cu];
        float ii = sigmoidf_(gi), ff = sigmoidf_(gf), gv = tanhf(gg), oo = sigmoidf_(go);
        c_reg = ff*c_reg + ii*gv;
        unsigned hb = f2bf(oo * tanhf(c_reg));
        unsigned o1 = (unsigned)__shfl_down((int)hb, 1);
        unsigned o2 = (unsigned)__shfl_down((int)hb, 2);
        unsigned o3 = (unsigned)__shfl_down((int)hb, 3);
        if (cu == 0) {
          unsigned long long v = (unsigned long long)(hb | (o1 << 16))
                               | ((unsigned long long)(o2 | (o3 << 16)) << 32);
          __hip_atomic_store((unsigned long long*)(h0g + (size_t)(t+1)*HS_SHORTS + pub16),
                             v, __ATOMIC_RELAXED, SCOPE_AG);
        }
      }
    } else {
      if (t >= 1) {
        float gi = sG1a[h][cb][cu]    + sG1b[h][cb][cu]    + sB1[cu];
        float gf = sG1a[h][cb][4+cu]  + sG1b[h][cb][4+cu]  + sB1[4+cu];
        float gg = sG1a[h][cb][8+cu]  + sG1b[h][cb][8+cu]  + sB1[8+cu];
        float go = sG1a[h][cb][12+cu] + sG1b[h][cb][12+cu] + sB1[12+cu];
        float ii = sigmoidf_(gi), ff = sigmoidf_(gf), gv = tanhf(gg), oo = sigmoidf_(go);
        c_reg = ff*c_reg + ii*gv;
        unsigned hb = f2bf(oo * tanhf(c_reg));
        unsigned o1 = (unsigned)__shfl_down((int)hb, 1);
        unsigned o2 = (unsigned)__shfl_down((int)hb, 2);
        unsigned o3 = (unsigned)__shfl_down((int)hb, 3);
        if (cu == 0) {
          unsigned long long v = (unsigned long long)(hb | (o1 << 16))
                               | ((unsigned long long)(o2 | (o3 << 16)) << 32);
          __hip_atomic_store((unsigned long long*)(h1g + (size_t)t*HS_SHORTS + pub16),
                             v, __ATOMIC_RELAXED, SCOPE_AG);
        }
      }
    }
    // ---- barP: publishes at LLC before flag (manual vmcnt drain) ----
    VM0();
    if (lane == 0)
      __hip_atomic_fetch_add(&sCnt[2+h], 1u, __ATOMIC_RELEASE, SCOPE_WG);
    if (role == 0) {   // wave h*4: waits for all 4 arrivals, then flags
      while (__hip_atomic_load(&sCnt[2+h], __ATOMIC_ACQUIRE, SCOPE_WG) < 4u*(unsigned)(t+1)) {}
      SCHED();
      if (lane == 0)
        __hip_atomic_store(&gfg[(unsigned)wg * FLAG_STRIDE], (unsigned)(t+1),
                           __ATOMIC_RELAXED, SCOPE_AG);
    }
    // ---- grid poll: every wave, 4 flags/lane (256 wgs), batched loads ----
    {
      const unsigned need = (unsigned)(t+1);
      for (;;) {
        unsigned f0 = __hip_atomic_load(&gfg[(unsigned)lane*FLAG_STRIDE],        __ATOMIC_RELAXED, SCOPE_AG);
        unsigned f1 = __hip_atomic_load(&gfg[(unsigned)(lane+64)*FLAG_STRIDE],   __ATOMIC_RELAXED, SCOPE_AG);
        unsigned f2 = __hip_atomic_load(&gfg[(unsigned)(lane+128)*FLAG_STRIDE],  __ATOMIC_RELAXED, SCOPE_AG);
        unsigned f3 = __hip_atomic_load(&gfg[(unsigned)(lane+192)*FLAG_STRIDE],  __ATOMIC_RELAXED, SCOPE_AG);
        if (__all(f0 >= need && f1 >= need && f2 >= need && f3 >= need)) break;
        __builtin_amdgcn_s_sleep(1);
      }
      SCHED();
    }
  }

  // ---- FC + repetition penalty (own group's h1[127] = slot 128) ----
  {
    const unsigned short* ab = h1g + (size_t)128*HS_SHORTS + lane*8;
    for (int tile = wg*4 + role; tile < NV/16; tile += 1024) {
      int c0 = tile*16;
      const float* wb = fc_w + (size_t)(c0 + lr)*NH + lq*8;
      f32x4 acc0 = {0.f,0.f,0.f,0.f}, acc1 = {0.f,0.f,0.f,0.f};
      #pragma unroll 4
      for (int kk = 0; kk < 32; ++kk) {
        bf16x8 bfv = pack8(*(const float4*)(wb + kk*32), *(const float4*)(wb + kk*32 + 4));
        acc0 = MFMA(*(const bf16x8*)(ab + kk*512),         bfv, acc0);
        acc1 = MFMA(*(const bf16x8*)(ab + 16384 + kk*512), bfv, acc1);
      }
      int c = c0 + lr;
      float fb = fc_b[c];
      #pragma unroll
      for (int r = 0; r < 4; ++r) {
        int b0 = h*32 + lq*4 + r;          // rb = 0
        int b1 = b0 + 16;                  // rb = 1
        unsigned cnt0 = counts[(size_t)b0*NV + c];
        unsigned cnt1 = counts[(size_t)b1*NV + c];
        out[(size_t)b0*NV + c] = (acc0[r] + fb) * exp2f(-0.26303440583379378f * (float)cnt0);
        out[(size_t)b1*NV + c] = (acc1[r] + fb) * exp2f(-0.26303440583379378f * (float)cnt1);
      }
    }
  }
}

extern "C" void kernel_launch(void* const* d_in, const int* in_sizes, int n_in,
                              void* d_out, int out_size, void* d_ws, size_t ws_size,
                              hipStream_t stream) {
  const int*   x     = (const int*)  d_in[0];
  const float* emb   = (const float*)d_in[1];
  const float* w_ih0 = (const float*)d_in[2];
  const float* w_hh0 = (const float*)d_in[3];
  const float* b_ih0 = (const float*)d_in[4];
  const float* b_hh0 = (const float*)d_in[5];
  const float* w_ih1 = (const float*)d_in[6];
  const float* w_hh1 = (const float*)d_in[7];
  const float* b_ih1 = (const float*)d_in[8];
  const float* b_hh1 = (const float*)d_in[9];
  const float* fc_w  = (const float*)d_in[10];
  const float* fc_b  = (const float*)d_in[11];
  if (ws_size < WS_NEEDED) return;
  unsigned char* ws = (unsigned char*)d_ws;
  (void)hipMemsetAsync(ws, 0, WS_H0, stream);                          // all flag arrays
  (void)hipMemsetAsync(ws + WS_H0, 0, 65536, stream);                  // hist0 g0 slot 0
  (void)hipMemsetAsync(ws + WS_H0 + 129u*65536u, 0, 65536, stream);    // hist0 g1 slot 0
  (void)hipMemsetAsync(ws + WS_H1, 0, 65536, stream);                  // hist1 g0 slot 0
  (void)hipMemsetAsync(ws + WS_H1 + 129u*65536u, 0, 65536, stream);    // hist1 g1 slot 0
  (void)hipMemsetAsync(ws + WS_CNT, 0, 4u*NB*NV, stream);              // token histogram
  hipLaunchKernelGGL(lstm_all, dim3(NWG), dim3(NTH), 0, stream,
                     x, emb, w_ih0, w_hh0, b_ih0, b_hh0,
                     w_ih1, w_hh1, b_ih1, b_hh1, fc_w, fc_b,
                     (float*)d_out, (unsigned char*)d_ws);
}

// Round 16
// 990.679 us; speedup vs baseline: 4.1173x; 2.0969x over previous
//
#include <hip/hip_runtime.h>
#include <hip/hip_bf16.h>
#include <stdint.h>

// Problem constants
#define NB 64      // batch
#define NT 128     // seq len
#define NE 512     // embed
#define NH 1024    // hidden
#define NV 32000   // vocab
#define NM (NB*NT) // 8192 flattened (t-major: m = t*64 + b)

// Kernel config: 2 independent batch-groups of 128 wgs. Group g = wg>>7 owns
// batches [32g, 32g+32); each wg computes 8 hidden units x 32 batches.
#define NWG 256
#define NTH 512
#define WPG 128            // wgs per group
#define FLAG_STRIDE 32u    // one flag per 128-B LLC line

// History half-slots per group, write-once, FRAGMENT-MAJOR:
// shorts offset (rb,kk,lane,j) = ((rb*32+kk)*64+lane)*8+j holds
// h[g*32 + rb*16 + (lane&15)][kk*32 + (lane>>4)*8 + j].
#define HS_SHORTS 32768u                        // 64 KB half-slot
#define GSTRIDE_SH (129u*HS_SHORTS)             // shorts per group hist
#define WS_FLAGS_S 0u                           // 32 KB: startup flags (256 lines)
#define WS_FLAGS_G 32768u                       // 32 KB: per-group arrival flags
#define WS_H0      65536u
#define WS_H1      (WS_H0 + 2u*129u*65536u)     // +16,908,288
#define WS_CNT     (WS_H1 + 2u*129u*65536u)
#define WS_XS0     (WS_CNT + 4u*NB*NV)
#define WS_NEEDED  (WS_XS0 + 2u*NM*NE)

typedef __attribute__((ext_vector_type(8))) short bf16x8;
typedef __attribute__((ext_vector_type(4))) float f32x4;

#define SCOPE_AG  __HIP_MEMORY_SCOPE_AGENT

__device__ __forceinline__ unsigned short f2bf(float f) {
  unsigned u = __float_as_uint(f);
  u += 0x7FFFu + ((u >> 16) & 1u);   // round-nearest-even
  return (unsigned short)(u >> 16);
}
__device__ __forceinline__ float sigmoidf_(float x) {
  return 1.0f / (1.0f + expf(-x));
}
__device__ __forceinline__ bf16x8 pack8(float4 a, float4 b) {
  bf16x8 v;
  v[0]=(short)f2bf(a.x); v[1]=(short)f2bf(a.y); v[2]=(short)f2bf(a.z); v[3]=(short)f2bf(a.w);
  v[4]=(short)f2bf(b.x); v[5]=(short)f2bf(b.y); v[6]=(short)f2bf(b.z); v[7]=(short)f2bf(b.w);
  return v;
}

#define MFMA(a,b,c) __builtin_amdgcn_mfma_f32_16x16x32_bf16((a),(b),(c),0,0,0)

__global__ void __launch_bounds__(NTH, 2)
lstm_all(const int* __restrict__ x, const float* __restrict__ emb,
         const float* __restrict__ w_ih0, const float* __restrict__ w_hh0,
         const float* __restrict__ b_ih0, const float* __restrict__ b_hh0,
         const float* __restrict__ w_ih1, const float* __restrict__ w_hh1,
         const float* __restrict__ b_ih1, const float* __restrict__ b_hh1,
         const float* __restrict__ fc_w, const float* __restrict__ fc_b,
         float* __restrict__ out, unsigned char* __restrict__ wsb)
{
  // LDS ~145 KB: weight slices in MFMA-fragment order [(ct)][kk][lane][8]
  __shared__ unsigned short sWih1[2*32*64*8];   // 64 KB: w_ih1 ct0+ct1
  __shared__ unsigned short sWhh0c1[32*64*8];   // 32 KB: w_hh0 ct1
  __shared__ unsigned short sWhh1c1[32*64*8];   // 32 KB: w_hh1 ct1
  __shared__ float sG0[32][32], sG1a[32][32], sG1b[32][32], sGih[32][32];
  __shared__ float sB0[32], sB1[32];
  __shared__ alignas(16) unsigned short sH0[32][8], sH1[32][8];

  const int wg  = blockIdx.x;
  const int tid = threadIdx.x;
  const int wave = tid >> 6, lane = tid & 63;
  const int lr = lane & 15, lq = lane >> 4;
  const int g  = wg >> 7;          // batch group
  const int wgl = wg & 127;        // wg within group (unit base = wgl*8)

  unsigned* flagsS = (unsigned*)(wsb + WS_FLAGS_S);
  unsigned* gf     = (unsigned*)(wsb + WS_FLAGS_G) + (unsigned)g*WPG*FLAG_STRIDE;
  unsigned short* h0g = (unsigned short*)(wsb + WS_H0) + (size_t)g*GSTRIDE_SH;
  unsigned short* h1g = (unsigned short*)(wsb + WS_H1) + (size_t)g*GSTRIDE_SH;
  unsigned* counts = (unsigned*)(wsb + WS_CNT);
  unsigned short* xs0 = (unsigned short*)(wsb + WS_XS0);

  // ---- breg: step-invariant B-fragments (ct0 of the wave's weight matrix) ----
  // w2/w3: w_hh0 ct0; w0/w1: w_hh1 ct0; w4/w5: w_ih0 ct0(kk<16)+ct1(kk>=16).
  bf16x8 breg[32];
  {
    const int ggr0 = (lr >> 3)*NH + wgl*8 + (lr & 7);          // col c = lr
    const int ggr1 = (2 + (lr >> 3))*NH + wgl*8 + (lr & 7);    // col c = 16+lr
    if (wave == 2 || wave == 3) {
      const float* src = w_hh0 + (size_t)ggr0*NH + lq*8;
      #pragma unroll
      for (int kk = 0; kk < 32; ++kk)
        breg[kk] = pack8(*(const float4*)(src + kk*32), *(const float4*)(src + kk*32 + 4));
    } else if (wave == 0 || wave == 1) {
      const float* src = w_hh1 + (size_t)ggr0*NH + lq*8;
      #pragma unroll
      for (int kk = 0; kk < 32; ++kk)
        breg[kk] = pack8(*(const float4*)(src + kk*32), *(const float4*)(src + kk*32 + 4));
    } else if (wave == 4 || wave == 5) {
      const float* s0 = w_ih0 + (size_t)ggr0*NE + lq*8;
      const float* s1 = w_ih0 + (size_t)ggr1*NE + lq*8;
      #pragma unroll
      for (int kk = 0; kk < 16; ++kk) {
        breg[kk]    = pack8(*(const float4*)(s0 + kk*32), *(const float4*)(s0 + kk*32 + 4));
        breg[16+kk] = pack8(*(const float4*)(s1 + kk*32), *(const float4*)(s1 + kk*32 + 4));
      }
    }
  }

  // ---- gather embeddings -> xs0 (bf16, per-group fragment-major), sc1 ----
  for (int i = wg*NTH + tid; i < NM*(NE/8); i += NWG*NTH) {
    int m = i >> 6;
    int e8 = (i & 63) << 3;
    int t = m >> 6, b = m & 63;
    int tok = x[b*NT + t];
    const float* s = emb + (size_t)tok*NE + e8;
    union { bf16x8 v8; unsigned long long u[2]; } u;
    u.v8 = pack8(*(const float4*)s, *(const float4*)(s + 4));
    int gg = b >> 5, bb = b & 31;
    size_t off = ((size_t)((gg*NT + t)*2 + (bb >> 4)))*8192
               + ((size_t)((e8 >> 5)*64 + ((e8 >> 3) & 3)*16 + (bb & 15)))*8;
    unsigned long long* dst = (unsigned long long*)(xs0 + off);
    __hip_atomic_store(dst,   u.u[0], __ATOMIC_RELAXED, SCOPE_AG);
    __hip_atomic_store(dst+1, u.u[1], __ATOMIC_RELAXED, SCOPE_AG);
  }

  // ---- weight slices -> LDS in fragment order ----
  for (int i = tid; i < 2*32*64; i += NTH) {        // sWih1 ct0+ct1
    int ct = i >> 11, kk = (i >> 6) & 31, l = i & 63;
    int glr = l & 15, glq = l >> 4;
    int c = ct*16 + glr;
    int ggr = (c >> 3)*NH + wgl*8 + (c & 7);
    const float* p = w_ih1 + (size_t)ggr*NH + kk*32 + glq*8;
    ((bf16x8*)sWih1)[i] = pack8(*(const float4*)p, *(const float4*)(p + 4));
  }
  for (int i = tid; i < 32*64; i += NTH) {          // sWhh0c1 / sWhh1c1
    int kk = i >> 6, l = i & 63;
    int glr = l & 15, glq = l >> 4;
    int ggr = (2 + (glr >> 3))*NH + wgl*8 + (glr & 7);   // col c = 16+glr
    const float* p0 = w_hh0 + (size_t)ggr*NH + kk*32 + glq*8;
    const float* p1 = w_hh1 + (size_t)ggr*NH + kk*32 + glq*8;
    ((bf16x8*)sWhh0c1)[i] = pack8(*(const float4*)p0, *(const float4*)(p0 + 4));
    ((bf16x8*)sWhh1c1)[i] = pack8(*(const float4*)p1, *(const float4*)(p1 + 4));
  }
  if (tid < 32) {
    int g2 = (tid >> 3)*NH + wgl*8 + (tid & 7);
    sB0[tid] = b_ih0[g2] + b_hh0[g2];
    sB1[tid] = b_ih1[g2] + b_hh1[g2];
  }
  // ---- token histogram ----
  {
    int i = wg*NTH + tid;
    if (i < NB*NT) {
      int b = i >> 7;
      atomicAdd(&counts[(size_t)b*NV + x[i]], 1u);
    }
  }
  // ---- startup: GLOBAL barrier (gather written by all wgs) ----
  __syncthreads();
  if (tid == 0)
    __hip_atomic_store(&flagsS[(unsigned)wg * FLAG_STRIDE], 1u, __ATOMIC_RELAXED, SCOPE_AG);
  if (tid < NWG) {
    while (__hip_atomic_load(&flagsS[(unsigned)tid * FLAG_STRIDE], __ATOMIC_RELAXED, SCOPE_AG) < 1u)
      __builtin_amdgcn_s_sleep(8);
  }
  __syncthreads();

  // ---- scan: 129 steps, per-group barrier ----
  // w2/w3 (rb=w-2): A=hist0[t] -> a0ct0(breg) a0ct1(LDS) a1ct0 a1ct1(LDS)
  // w0/w1 (rb=w):   A=hist1[t-1] -> a2ct0(breg) a2ct1(LDS)
  // w4/w5 (rb=w-4): A=xs[t] -> ai ct0/ct1 (breg)
  // cells tid<256: layer0 t; tid>=256: layer1 t-1. w6/w7 publish.
  float c_reg = 0.f;
  const int cbb = (tid & 255) >> 3, cu8 = tid & 7;
  for (int t = 0; t <= NT; ++t) {
    if (wave == 2 || wave == 3) {
      const int rb = wave - 2;
      const unsigned short* A = h0g + (size_t)t*HS_SHORTS + rb*16384 + lane*8;
      f32x4 a00 = {0.f,0.f,0.f,0.f}, a01 = {0.f,0.f,0.f,0.f};
      f32x4 a10 = {0.f,0.f,0.f,0.f}, a11 = {0.f,0.f,0.f,0.f};
      #pragma unroll
      for (int kk = 0; kk < 32; ++kk) {
        bf16x8 af = *(const bf16x8*)(A + kk*512);
        a00 = MFMA(af, breg[kk], a00);
        a01 = MFMA(af, ((const bf16x8*)sWhh0c1)[kk*64 + lane], a01);
        a10 = MFMA(af, ((const bf16x8*)sWih1)[kk*64 + lane], a10);
        a11 = MFMA(af, ((const bf16x8*)sWih1)[(32+kk)*64 + lane], a11);
      }
      #pragma unroll
      for (int r = 0; r < 4; ++r) {
        int row = rb*16 + lq*4 + r;
        sG0 [row][lr]    = a00[r];
        sG0 [row][16+lr] = a01[r];
        sG1a[row][lr]    = a10[r];
        sG1a[row][16+lr] = a11[r];
      }
    } else if (wave == 0 || wave == 1) {
      if (t >= 1) {
        const int rb = wave;
        const unsigned short* A = h1g + (size_t)(t-1)*HS_SHORTS + rb*16384 + lane*8;
        f32x4 a20 = {0.f,0.f,0.f,0.f}, a21 = {0.f,0.f,0.f,0.f};
        #pragma unroll
        for (int kk = 0; kk < 32; ++kk) {
          bf16x8 af = *(const bf16x8*)(A + kk*512);
          a20 = MFMA(af, breg[kk], a20);
          a21 = MFMA(af, ((const bf16x8*)sWhh1c1)[kk*64 + lane], a21);
        }
        #pragma unroll
        for (int r = 0; r < 4; ++r) {
          int row = rb*16 + lq*4 + r;
          sG1b[row][lr]    = a20[r];
          sG1b[row][16+lr] = a21[r];
        }
      }
    } else if (wave == 4 || wave == 5) {
      if (t < NT) {
        const int rb = wave - 4;
        const unsigned short* A = xs0 + ((size_t)((g*NT + t)*2 + rb))*8192 + lane*8;
        f32x4 ai0 = {0.f,0.f,0.f,0.f}, ai1 = {0.f,0.f,0.f,0.f};
        #pragma unroll
        for (int kk = 0; kk < 16; ++kk) {
          bf16x8 af = *(const bf16x8*)(A + kk*512);
          ai0 = MFMA(af, breg[kk], ai0);
          ai1 = MFMA(af, breg[16+kk], ai1);
        }
        #pragma unroll
        for (int r = 0; r < 4; ++r) {
          int row = rb*16 + lq*4 + r;
          sGih[row][lr]    = ai0[r];
          sGih[row][16+lr] = ai1[r];
        }
      }
    }
    __syncthreads();
    // ---- cells ----
    if (tid < 256) {
      if (t < NT) {
        float gi = sG0[cbb][cu8]    + sGih[cbb][cu8]    + sB0[cu8];
        float gf = sG0[cbb][8+cu8]  + sGih[cbb][8+cu8]  + sB0[8+cu8];
        float gg = sG0[cbb][16+cu8] + sGih[cbb][16+cu8] + sB0[16+cu8];
        float go = sG0[cbb][24+cu8] + sGih[cbb][24+cu8] + sB0[24+cu8];
        float ii = sigmoidf_(gi), ff = sigmoidf_(gf), gv = tanhf(gg), oo = sigmoidf_(go);
        c_reg = ff*c_reg + ii*gv;
        sH0[cbb][cu8] = f2bf(oo * tanhf(c_reg));
      }
    } else {
      if (t >= 1) {
        float gi = sG1a[cbb][cu8]    + sG1b[cbb][cu8]    + sB1[cu8];
        float gf = sG1a[cbb][8+cu8]  + sG1b[cbb][8+cu8]  + sB1[8+cu8];
        float gg = sG1a[cbb][16+cu8] + sG1b[cbb][16+cu8] + sB1[16+cu8];
        float go = sG1a[cbb][24+cu8] + sG1b[cbb][24+cu8] + sB1[24+cu8];
        float ii = sigmoidf_(gi), ff = sigmoidf_(gf), gv = tanhf(gg), oo = sigmoidf_(go);
        c_reg = ff*c_reg + ii*gv;
        sH1[cbb][cu8] = f2bf(oo * tanhf(c_reg));
      }
    }
    __syncthreads();
    // ---- publish (w6: hist0 slot t+1, w7: hist1 slot t), 8 B sc1/lane ----
    if (wave == 6 && t < NT) {
      int bb = lane >> 1, j0 = (lane & 1)*4;
      unsigned long long v = *(const unsigned long long*)&sH0[bb][j0];
      size_t off = ((size_t)(((bb >> 4)*32 + (wgl >> 2))*64 + (wgl & 3)*16 + (bb & 15)))*8 + j0;
      __hip_atomic_store((unsigned long long*)(h0g + (size_t)(t+1)*HS_SHORTS + off),
                         v, __ATOMIC_RELAXED, SCOPE_AG);
    }
    if (wave == 7 && t >= 1) {
      int bb = lane >> 1, j0 = (lane & 1)*4;
      unsigned long long v = *(const unsigned long long*)&sH1[bb][j0];
      size_t off = ((size_t)(((bb >> 4)*32 + (wgl >> 2))*64 + (wgl & 3)*16 + (bb & 15)))*8 + j0;
      __hip_atomic_store((unsigned long long*)(h1g + (size_t)t*HS_SHORTS + off),
                         v, __ATOMIC_RELAXED, SCOPE_AG);
    }
    // ---- per-group barrier (r5 skeleton: flag + 128 parallel pollers) ----
    __syncthreads();
    if (tid == 0)
      __hip_atomic_store(&gf[(unsigned)wgl * FLAG_STRIDE], (unsigned)(t+1),
                         __ATOMIC_RELAXED, SCOPE_AG);
    if (tid < WPG) {
      while (__hip_atomic_load(&gf[(unsigned)tid * FLAG_STRIDE],
                               __ATOMIC_RELAXED, SCOPE_AG) < (unsigned)(t+1))
        __builtin_amdgcn_s_sleep(4);
    }
    __syncthreads();
  }

  // ---- FC + repetition penalty (group's h1[127] = hist1 slot 128) ----
  {
    const unsigned short* ab = h1g + (size_t)128*HS_SHORTS + lane*8;
    for (int tile = wgl*8 + wave; tile < NV/16; tile += WPG*8) {
      int c0 = tile*16;
      const float* wb = fc_w + (size_t)(c0 + lr)*NH + lq*8;
      f32x4 acc0 = {0.f,0.f,0.f,0.f}, acc1 = {0.f,0.f,0.f,0.f};
      #pragma unroll 4
      for (int kk = 0; kk < 32; ++kk) {
        bf16x8 bfv = pack8(*(const float4*)(wb + kk*32), *(const float4*)(wb + kk*32 + 4));
        acc0 = MFMA(*(const bf16x8*)(ab + kk*512),         bfv, acc0);
        acc1 = MFMA(*(const bf16x8*)(ab + 16384 + kk*512), bfv, acc1);
      }
      int c = c0 + lr;
      float fb = fc_b[c];
      #pragma unroll
      for (int r = 0; r < 4; ++r) {
        int b0 = g*32 + lq*4 + r;          // rb = 0
        int b1 = b0 + 16;                  // rb = 1
        unsigned cnt0 = counts[(size_t)b0*NV + c];
        unsigned cnt1 = counts[(size_t)b1*NV + c];
        out[(size_t)b0*NV + c] = (acc0[r] + fb) * exp2f(-0.26303440583379378f * (float)cnt0);
        out[(size_t)b1*NV + c] = (acc1[r] + fb) * exp2f(-0.26303440583379378f * (float)cnt1);
      }
    }
  }
}

extern "C" void kernel_launch(void* const* d_in, const int* in_sizes, int n_in,
                              void* d_out, int out_size, void* d_ws, size_t ws_size,
                              hipStream_t stream) {
  const int*   x     = (const int*)  d_in[0];
  const float* emb   = (const float*)d_in[1];
  const float* w_ih0 = (const float*)d_in[2];
  const float* w_hh0 = (const float*)d_in[3];
  const float* b_ih0 = (const float*)d_in[4];
  const float* b_hh0 = (const float*)d_in[5];
  const float* w_ih1 = (const float*)d_in[6];
  const float* w_hh1 = (const float*)d_in[7];
  const float* b_ih1 = (const float*)d_in[8];
  const float* b_hh1 = (const float*)d_in[9];
  const float* fc_w  = (const float*)d_in[10];
  const float* fc_b  = (const float*)d_in[11];
  if (ws_size < WS_NEEDED) return;
  unsigned char* ws = (unsigned char*)d_ws;
  (void)hipMemsetAsync(ws, 0, WS_H0, stream);                          // both flag arrays
  (void)hipMemsetAsync(ws + WS_H0, 0, 65536, stream);                  // hist0 g0 slot 0
  (void)hipMemsetAsync(ws + WS_H0 + 129u*65536u, 0, 65536, stream);    // hist0 g1 slot 0
  (void)hipMemsetAsync(ws + WS_H1, 0, 65536, stream);                  // hist1 g0 slot 0
  (void)hipMemsetAsync(ws + WS_H1 + 129u*65536u, 0, 65536, stream);    // hist1 g1 slot 0
  (void)hipMemsetAsync(ws + WS_CNT, 0, 4u*NB*NV, stream);              // token histogram
  hipLaunchKernelGGL(lstm_all, dim3(NWG), dim3(NTH), 0, stream,
                     x, emb, w_ih0, w_hh0, b_ih0, b_hh0,
                     w_ih1, w_hh1, b_ih1, b_hh1, fc_w, fc_b,
                     (float*)d_out, (unsigned char*)d_ws);
}

// Round 17
// 986.179 us; speedup vs baseline: 4.1361x; 1.0046x over previous
//
#include <hip/hip_runtime.h>
#include <hip/hip_bf16.h>
#include <stdint.h>

// Problem constants
#define NB 64      // batch
#define NT 128     // seq len
#define NE 512     // embed
#define NH 1024    // hidden
#define NV 32000   // vocab
#define NM (NB*NT) // 8192 flattened (t-major: m = t*64 + b)

// Kernel config: 2 independent batch-groups of 128 wgs. Group g = wg>>7 owns
// batches [32g, 32g+32); each wg computes 8 hidden units x 32 batches.
#define NWG 256
#define NTH 512
#define WPG 128            // wgs per group
#define FLAG_STRIDE 32u    // one flag per 128-B LLC line

// History half-slots per group, write-once, FRAGMENT-MAJOR:
// shorts offset (rb,kk,lane,j) = ((rb*32+kk)*64+lane)*8+j holds
// h[g*32 + rb*16 + (lane&15)][kk*32 + (lane>>4)*8 + j].
#define HS_SHORTS 32768u                        // 64 KB half-slot
#define GSTRIDE_SH (129u*HS_SHORTS)             // shorts per group hist
#define WS_FLAGS_S 0u                           // 32 KB: startup flags (256 lines)
#define WS_FLAGS_G 32768u                       // 32 KB: per-group arrival flags
#define WS_H0      65536u
#define WS_H1      (WS_H0 + 2u*129u*65536u)     // +16,908,288
#define WS_CNT     (WS_H1 + 2u*129u*65536u)
#define WS_XS0     (WS_CNT + 4u*NB*NV)
#define WS_NEEDED  (WS_XS0 + 2u*NM*NE)

typedef __attribute__((ext_vector_type(8))) short bf16x8;
typedef __attribute__((ext_vector_type(4))) float f32x4;

#define SCOPE_AG  __HIP_MEMORY_SCOPE_AGENT

__device__ __forceinline__ unsigned short f2bf(float f) {
  unsigned u = __float_as_uint(f);
  u += 0x7FFFu + ((u >> 16) & 1u);   // round-nearest-even
  return (unsigned short)(u >> 16);
}
__device__ __forceinline__ float sigmoidf_(float x) {
  return 1.0f / (1.0f + expf(-x));
}
__device__ __forceinline__ bf16x8 pack8(float4 a, float4 b) {
  bf16x8 v;
  v[0]=(short)f2bf(a.x); v[1]=(short)f2bf(a.y); v[2]=(short)f2bf(a.z); v[3]=(short)f2bf(a.w);
  v[4]=(short)f2bf(b.x); v[5]=(short)f2bf(b.y); v[6]=(short)f2bf(b.z); v[7]=(short)f2bf(b.w);
  return v;
}

#define MFMA(a,b,c) __builtin_amdgcn_mfma_f32_16x16x32_bf16((a),(b),(c),0,0,0)

__global__ void __launch_bounds__(NTH, 2)
lstm_all(const int* __restrict__ x, const float* __restrict__ emb,
         const float* __restrict__ w_ih0, const float* __restrict__ w_hh0,
         const float* __restrict__ b_ih0, const float* __restrict__ b_hh0,
         const float* __restrict__ w_ih1, const float* __restrict__ w_hh1,
         const float* __restrict__ b_ih1, const float* __restrict__ b_hh1,
         const float* __restrict__ fc_w, const float* __restrict__ fc_b,
         float* __restrict__ out, unsigned char* __restrict__ wsb)
{
  // LDS ~145 KB: weight slices in MFMA-fragment order [(ct)][kk][lane][8]
  __shared__ unsigned short sWih1[2*32*64*8];   // 64 KB: w_ih1 ct0+ct1
  __shared__ unsigned short sWhh0c1[32*64*8];   // 32 KB: w_hh0 ct1
  __shared__ unsigned short sWhh1c1[32*64*8];   // 32 KB: w_hh1 ct1
  __shared__ float sG0[32][32], sG1a[32][32], sG1b[32][32], sGih[32][32];
  __shared__ float sB0[32], sB1[32];
  __shared__ alignas(16) unsigned short sH0[32][8], sH1[32][8];

  const int wg  = blockIdx.x;
  const int tid = threadIdx.x;
  const int wave = tid >> 6, lane = tid & 63;
  const int lr = lane & 15, lq = lane >> 4;
  const int g  = wg >> 7;          // batch group
  const int wgl = wg & 127;        // wg within group (unit base = wgl*8)

  unsigned* flagsS = (unsigned*)(wsb + WS_FLAGS_S);
  unsigned* gf     = (unsigned*)(wsb + WS_FLAGS_G) + (unsigned)g*WPG*FLAG_STRIDE;
  unsigned short* h0g = (unsigned short*)(wsb + WS_H0) + (size_t)g*GSTRIDE_SH;
  unsigned short* h1g = (unsigned short*)(wsb + WS_H1) + (size_t)g*GSTRIDE_SH;
  unsigned* counts = (unsigned*)(wsb + WS_CNT);
  unsigned short* xs0 = (unsigned short*)(wsb + WS_XS0);

  // ---- breg: step-invariant B-fragments (ct0 of the wave's weight matrix) ----
  // w2/w3: w_hh0 ct0; w0/w1: w_hh1 ct0; w4/w5: w_ih0 ct0(kk<16)+ct1(kk>=16).
  bf16x8 breg[32];
  {
    const int ggr0 = (lr >> 3)*NH + wgl*8 + (lr & 7);          // col c = lr
    const int ggr1 = (2 + (lr >> 3))*NH + wgl*8 + (lr & 7);    // col c = 16+lr
    if (wave == 2 || wave == 3) {
      const float* src = w_hh0 + (size_t)ggr0*NH + lq*8;
      #pragma unroll
      for (int kk = 0; kk < 32; ++kk)
        breg[kk] = pack8(*(const float4*)(src + kk*32), *(const float4*)(src + kk*32 + 4));
    } else if (wave == 0 || wave == 1) {
      const float* src = w_hh1 + (size_t)ggr0*NH + lq*8;
      #pragma unroll
      for (int kk = 0; kk < 32; ++kk)
        breg[kk] = pack8(*(const float4*)(src + kk*32), *(const float4*)(src + kk*32 + 4));
    } else if (wave == 4 || wave == 5) {
      const float* s0 = w_ih0 + (size_t)ggr0*NE + lq*8;
      const float* s1 = w_ih0 + (size_t)ggr1*NE + lq*8;
      #pragma unroll
      for (int kk = 0; kk < 16; ++kk) {
        breg[kk]    = pack8(*(const float4*)(s0 + kk*32), *(const float4*)(s0 + kk*32 + 4));
        breg[16+kk] = pack8(*(const float4*)(s1 + kk*32), *(const float4*)(s1 + kk*32 + 4));
      }
    }
  }

  // ---- gather embeddings -> xs0 (bf16, per-group fragment-major), sc1 ----
  for (int i = wg*NTH + tid; i < NM*(NE/8); i += NWG*NTH) {
    int m = i >> 6;
    int e8 = (i & 63) << 3;
    int t = m >> 6, b = m & 63;
    int tok = x[b*NT + t];
    const float* s = emb + (size_t)tok*NE + e8;
    union { bf16x8 v8; unsigned long long u[2]; } u;
    u.v8 = pack8(*(const float4*)s, *(const float4*)(s + 4));
    int gg = b >> 5, bb = b & 31;
    size_t off = ((size_t)((gg*NT + t)*2 + (bb >> 4)))*8192
               + ((size_t)((e8 >> 5)*64 + ((e8 >> 3) & 3)*16 + (bb & 15)))*8;
    unsigned long long* dst = (unsigned long long*)(xs0 + off);
    __hip_atomic_store(dst,   u.u[0], __ATOMIC_RELAXED, SCOPE_AG);
    __hip_atomic_store(dst+1, u.u[1], __ATOMIC_RELAXED, SCOPE_AG);
  }

  // ---- weight slices -> LDS in fragment order ----
  for (int i = tid; i < 2*32*64; i += NTH) {        // sWih1 ct0+ct1
    int ct = i >> 11, kk = (i >> 6) & 31, l = i & 63;
    int glr = l & 15, glq = l >> 4;
    int c = ct*16 + glr;
    int ggr = (c >> 3)*NH + wgl*8 + (c & 7);
    const float* p = w_ih1 + (size_t)ggr*NH + kk*32 + glq*8;
    ((bf16x8*)sWih1)[i] = pack8(*(const float4*)p, *(const float4*)(p + 4));
  }
  for (int i = tid; i < 32*64; i += NTH) {          // sWhh0c1 / sWhh1c1
    int kk = i >> 6, l = i & 63;
    int glr = l & 15, glq = l >> 4;
    int ggr = (2 + (glr >> 3))*NH + wgl*8 + (glr & 7);   // col c = 16+glr
    const float* p0 = w_hh0 + (size_t)ggr*NH + kk*32 + glq*8;
    const float* p1 = w_hh1 + (size_t)ggr*NH + kk*32 + glq*8;
    ((bf16x8*)sWhh0c1)[i] = pack8(*(const float4*)p0, *(const float4*)(p0 + 4));
    ((bf16x8*)sWhh1c1)[i] = pack8(*(const float4*)p1, *(const float4*)(p1 + 4));
  }
  if (tid < 32) {
    int g2 = (tid >> 3)*NH + wgl*8 + (tid & 7);
    sB0[tid] = b_ih0[g2] + b_hh0[g2];
    sB1[tid] = b_ih1[g2] + b_hh1[g2];
  }
  // ---- token histogram ----
  {
    int i = wg*NTH + tid;
    if (i < NB*NT) {
      int b = i >> 7;
      atomicAdd(&counts[(size_t)b*NV + x[i]], 1u);
    }
  }
  // ---- startup: GLOBAL barrier (gather written by all wgs) ----
  __syncthreads();
  if (tid == 0)
    __hip_atomic_store(&flagsS[(unsigned)wg * FLAG_STRIDE], 1u, __ATOMIC_RELAXED, SCOPE_AG);
  if (tid < NWG) {
    while (__hip_atomic_load(&flagsS[(unsigned)tid * FLAG_STRIDE], __ATOMIC_RELAXED, SCOPE_AG) < 1u)
      __builtin_amdgcn_s_sleep(8);
  }
  __syncthreads();

  // ---- scan: 129 steps, per-group barrier ----
  // w2/w3 (rb=w-2): A=hist0[t] -> a0ct0(breg) a0ct1(LDS) a1ct0 a1ct1(LDS)
  // w0/w1 (rb=w):   A=hist1[t-1] -> a2ct0(breg) a2ct1(LDS)
  // w4/w5 (rb=w-4): A=xs[t] -> ai ct0/ct1 (breg)
  // cells tid<256: layer0 t; tid>=256: layer1 t-1. w6/w7 publish.
  float c_reg = 0.f;
  const int cbb = (tid & 255) >> 3, cu8 = tid & 7;
  for (int t = 0; t <= NT; ++t) {
    if (wave == 2 || wave == 3) {
      const int rb = wave - 2;
      const unsigned short* A = h0g + (size_t)t*HS_SHORTS + rb*16384 + lane*8;
      f32x4 a00 = {0.f,0.f,0.f,0.f}, a01 = {0.f,0.f,0.f,0.f};
      f32x4 a10 = {0.f,0.f,0.f,0.f}, a11 = {0.f,0.f,0.f,0.f};
      #pragma unroll
      for (int kk = 0; kk < 32; ++kk) {
        bf16x8 af = *(const bf16x8*)(A + kk*512);
        a00 = MFMA(af, breg[kk], a00);
        a01 = MFMA(af, ((const bf16x8*)sWhh0c1)[kk*64 + lane], a01);
        a10 = MFMA(af, ((const bf16x8*)sWih1)[kk*64 + lane], a10);
        a11 = MFMA(af, ((const bf16x8*)sWih1)[(32+kk)*64 + lane], a11);
      }
      #pragma unroll
      for (int r = 0; r < 4; ++r) {
        int row = rb*16 + lq*4 + r;
        sG0 [row][lr]    = a00[r];
        sG0 [row][16+lr] = a01[r];
        sG1a[row][lr]    = a10[r];
        sG1a[row][16+lr] = a11[r];
      }
    } else if (wave == 0 || wave == 1) {
      if (t >= 1) {
        const int rb = wave;
        const unsigned short* A = h1g + (size_t)(t-1)*HS_SHORTS + rb*16384 + lane*8;
        f32x4 a20 = {0.f,0.f,0.f,0.f}, a21 = {0.f,0.f,0.f,0.f};
        #pragma unroll
        for (int kk = 0; kk < 32; ++kk) {
          bf16x8 af = *(const bf16x8*)(A + kk*512);
          a20 = MFMA(af, breg[kk], a20);
          a21 = MFMA(af, ((const bf16x8*)sWhh1c1)[kk*64 + lane], a21);
        }
        #pragma unroll
        for (int r = 0; r < 4; ++r) {
          int row = rb*16 + lq*4 + r;
          sG1b[row][lr]    = a20[r];
          sG1b[row][16+lr] = a21[r];
        }
      }
    } else if (wave == 4 || wave == 5) {
      if (t < NT) {
        const int rb = wave - 4;
        const unsigned short* A = xs0 + ((size_t)((g*NT + t)*2 + rb))*8192 + lane*8;
        f32x4 ai0 = {0.f,0.f,0.f,0.f}, ai1 = {0.f,0.f,0.f,0.f};
        #pragma unroll
        for (int kk = 0; kk < 16; ++kk) {
          bf16x8 af = *(const bf16x8*)(A + kk*512);
          ai0 = MFMA(af, breg[kk], ai0);
          ai1 = MFMA(af, breg[16+kk], ai1);
        }
        #pragma unroll
        for (int r = 0; r < 4; ++r) {
          int row = rb*16 + lq*4 + r;
          sGih[row][lr]    = ai0[r];
          sGih[row][16+lr] = ai1[r];
        }
      }
    }
    __syncthreads();
    // ---- cells ----
    if (tid < 256) {
      if (t < NT) {
        float gi = sG0[cbb][cu8]    + sGih[cbb][cu8]    + sB0[cu8];
        float gf = sG0[cbb][8+cu8]  + sGih[cbb][8+cu8]  + sB0[8+cu8];
        float gg = sG0[cbb][16+cu8] + sGih[cbb][16+cu8] + sB0[16+cu8];
        float go = sG0[cbb][24+cu8] + sGih[cbb][24+cu8] + sB0[24+cu8];
        float ii = sigmoidf_(gi), ff = sigmoidf_(gf), gv = tanhf(gg), oo = sigmoidf_(go);
        c_reg = ff*c_reg + ii*gv;
        sH0[cbb][cu8] = f2bf(oo * tanhf(c_reg));
      }
    } else {
      if (t >= 1) {
        float gi = sG1a[cbb][cu8]    + sG1b[cbb][cu8]    + sB1[cu8];
        float gf = sG1a[cbb][8+cu8]  + sG1b[cbb][8+cu8]  + sB1[8+cu8];
        float gg = sG1a[cbb][16+cu8] + sG1b[cbb][16+cu8] + sB1[16+cu8];
        float go = sG1a[cbb][24+cu8] + sG1b[cbb][24+cu8] + sB1[24+cu8];
        float ii = sigmoidf_(gi), ff = sigmoidf_(gf), gv = tanhf(gg), oo = sigmoidf_(go);
        c_reg = ff*c_reg + ii*gv;
        sH1[cbb][cu8] = f2bf(oo * tanhf(c_reg));
      }
    }
    __syncthreads();
    // ---- publish (w6: hist0 slot t+1, w7: hist1 slot t), 8 B sc1/lane ----
    if (wave == 6 && t < NT) {
      int bb = lane >> 1, j0 = (lane & 1)*4;
      unsigned long long v = *(const unsigned long long*)&sH0[bb][j0];
      size_t off = ((size_t)(((bb >> 4)*32 + (wgl >> 2))*64 + (wgl & 3)*16 + (bb & 15)))*8 + j0;
      __hip_atomic_store((unsigned long long*)(h0g + (size_t)(t+1)*HS_SHORTS + off),
                         v, __ATOMIC_RELAXED, SCOPE_AG);
    }
    if (wave == 7 && t >= 1) {
      int bb = lane >> 1, j0 = (lane & 1)*4;
      unsigned long long v = *(const unsigned long long*)&sH1[bb][j0];
      size_t off = ((size_t)(((bb >> 4)*32 + (wgl >> 2))*64 + (wgl & 3)*16 + (bb & 15)))*8 + j0;
      __hip_atomic_store((unsigned long long*)(h1g + (size_t)t*HS_SHORTS + off),
                         v, __ATOMIC_RELAXED, SCOPE_AG);
    }
    // ---- per-group barrier (r5 skeleton: flag + 128 parallel pollers) ----
    __syncthreads();
    if (tid == 0)
      __hip_atomic_store(&gf[(unsigned)wgl * FLAG_STRIDE], (unsigned)(t+1),
                         __ATOMIC_RELAXED, SCOPE_AG);
    if (tid < WPG) {
      while (__hip_atomic_load(&gf[(unsigned)tid * FLAG_STRIDE],
                               __ATOMIC_RELAXED, SCOPE_AG) < (unsigned)(t+1))
        __builtin_amdgcn_s_sleep(4);
    }
    __syncthreads();
  }

  // ---- pre-FC GLOBAL barrier: both groups' h1[127] (slot 128) published ----
  if (tid == 0)
    __hip_atomic_store(&flagsS[(unsigned)wg * FLAG_STRIDE], 2u, __ATOMIC_RELAXED, SCOPE_AG);
  if (tid < NWG) {
    while (__hip_atomic_load(&flagsS[(unsigned)tid * FLAG_STRIDE], __ATOMIC_RELAXED, SCOPE_AG) < 2u)
      __builtin_amdgcn_s_sleep(4);
  }
  __syncthreads();

  // ---- FC + repetition penalty, fc_w read ONCE chip-wide ----
  // tile = wg*8 + wave strides all 2000 column-tiles exactly once; each wave
  // computes BOTH groups' batches (4 accumulators) over one fc_w stream.
  {
    const unsigned short* ab0 = (unsigned short*)(wsb + WS_H1) + (size_t)128*HS_SHORTS + lane*8;
    const unsigned short* ab1 = ab0 + GSTRIDE_SH;
    int tile = wg*8 + wave;
    if (tile < NV/16) {
      int c0 = tile*16;
      const float* wb = fc_w + (size_t)(c0 + lr)*NH + lq*8;
      f32x4 acc00 = {0.f,0.f,0.f,0.f}, acc01 = {0.f,0.f,0.f,0.f};
      f32x4 acc10 = {0.f,0.f,0.f,0.f}, acc11 = {0.f,0.f,0.f,0.f};
      #pragma unroll 4
      for (int kk = 0; kk < 32; ++kk) {
        bf16x8 bfv = pack8(*(const float4*)(wb + kk*32), *(const float4*)(wb + kk*32 + 4));
        acc00 = MFMA(*(const bf16x8*)(ab0 + kk*512),         bfv, acc00);
        acc01 = MFMA(*(const bf16x8*)(ab0 + 16384 + kk*512), bfv, acc01);
        acc10 = MFMA(*(const bf16x8*)(ab1 + kk*512),         bfv, acc10);
        acc11 = MFMA(*(const bf16x8*)(ab1 + 16384 + kk*512), bfv, acc11);
      }
      int c = c0 + lr;
      float fb = fc_b[c];
      #pragma unroll
      for (int r = 0; r < 4; ++r) {
        int b00 = lq*4 + r;                // g0 rb0
        int b01 = b00 + 16;                // g0 rb1
        int b10 = b00 + 32;                // g1 rb0
        int b11 = b00 + 48;                // g1 rb1
        unsigned cnt00 = counts[(size_t)b00*NV + c];
        unsigned cnt01 = counts[(size_t)b01*NV + c];
        unsigned cnt10 = counts[(size_t)b10*NV + c];
        unsigned cnt11 = counts[(size_t)b11*NV + c];
        out[(size_t)b00*NV + c] = (acc00[r] + fb) * exp2f(-0.26303440583379378f * (float)cnt00);
        out[(size_t)b01*NV + c] = (acc01[r] + fb) * exp2f(-0.26303440583379378f * (float)cnt01);
        out[(size_t)b10*NV + c] = (acc10[r] + fb) * exp2f(-0.26303440583379378f * (float)cnt10);
        out[(size_t)b11*NV + c] = (acc11[r] + fb) * exp2f(-0.26303440583379378f * (float)cnt11);
      }
    }
  }
}

extern "C" void kernel_launch(void* const* d_in, const int* in_sizes, int n_in,
                              void* d_out, int out_size, void* d_ws, size_t ws_size,
                              hipStream_t stream) {
  const int*   x     = (const int*)  d_in[0];
  const float* emb   = (const float*)d_in[1];
  const float* w_ih0 = (const float*)d_in[2];
  const float* w_hh0 = (const float*)d_in[3];
  const float* b_ih0 = (const float*)d_in[4];
  const float* b_hh0 = (const float*)d_in[5];
  const float* w_ih1 = (const float*)d_in[6];
  const float* w_hh1 = (const float*)d_in[7];
  const float* b_ih1 = (const float*)d_in[8];
  const float* b_hh1 = (const float*)d_in[9];
  const float* fc_w  = (const float*)d_in[10];
  const float* fc_b  = (const float*)d_in[11];
  if (ws_size < WS_NEEDED) return;
  unsigned char* ws = (unsigned char*)d_ws;
  (void)hipMemsetAsync(ws, 0, WS_H0, stream);                          // both flag arrays
  (void)hipMemsetAsync(ws + WS_H0, 0, 65536, stream);                  // hist0 g0 slot 0
  (void)hipMemsetAsync(ws + WS_H0 + 129u*65536u, 0, 65536, stream);    // hist0 g1 slot 0
  (void)hipMemsetAsync(ws + WS_H1, 0, 65536, stream);                  // hist1 g0 slot 0
  (void)hipMemsetAsync(ws + WS_H1 + 129u*65536u, 0, 65536, stream);    // hist1 g1 slot 0
  (void)hipMemsetAsync(ws + WS_CNT, 0, 4u*NB*NV, stream);              // token histogram
  hipLaunchKernelGGL(lstm_all, dim3(NWG), dim3(NTH), 0, stream,
                     x, emb, w_ih0, w_hh0, b_ih0, b_hh0,
                     w_ih1, w_hh1, b_ih1, b_hh1, fc_w, fc_b,
                     (float*)d_out, (unsigned char*)d_ws);
}